// Round 7
// baseline (129.010 us; speedup 1.0000x reference)
//
#include <hip/hip_runtime.h>
#include <math.h>

// DiffKS: time-varying 7-tap sparse IIR.
//   y[n] = x[n] + sum_{i=0..6} block_i[n] * y[n - zc[n] - i],  zc in [37,97].
// Max lag 103 -> 103-sample state. Linear => segmented superposition:
//   phase1: ROUND-17: RUN-SPLIT. 512 blocks x 512 threads: block (bs,h)
//           evolves 52 of the 104 runs of segment bs. hist = 263x52 floats
//           = 54.7KB -> TWO blocks co-resident per CU (8 waves/SIMD, max
//           TLP). Rationale: rounds are LDS-throughput/lock-step bound
//           (~2000cy/round vs ~730cy byte floor; ds_read_b128 ~= 12cy each,
//           m134) -- r4/r5/r6 inner-loop rewrites all neutral. Only added
//           concurrency vs the same LDS pipe can close the gap: block B
//           issues while block A stalls at its barrier.
//           Wave = 4 samples x 13 quads; coeffs in registers (2 cached
//           samples/lane, 4 readlane broadcasts/round, mask-select).
//   phase2: serial state composition, coalesced split-K (round-8 spill-proof
//           macro: tvA/tvB always statically indexed).
//   phase3: exact per-segment re-run with known incoming state (256 blocks).
// DEAD ENDS (do not revisit): cross-block sync in-kernel (spin flags 124us,
// coop grid-sync 264us); Cg coeff detour (+16.8MB HBM); chunked hist layout
// (8-way write conflicts, 6.1M); instruction-form rewrites of phase1's loop
// (b64->b128, readlane, mirror rows: all neutral -- byte/lock-step bound).

#define B_    16
#define N_    16384
#define S_    16
#define NSEG  1024
#define NITER 28      // ceil(1024/37) for phase3
#define RUNS  104     // 103 unit columns + 1 particular
#define RUNS_H 52     // runs per phase1 block (run-split)
#define CHUNK 37      // min dependency distance (zc >= 37)
#define HROWS 263     // 256 ring rows + 7 mirror rows (rows 256..262 = 0..6)

#define TG_FLOATS (B_ * S_ * RUNS * RUNS)
#define ST_FLOATS (B_ * S_ * RUNS)

#define RL(v, l) __int_as_float(__builtin_amdgcn_readlane(__float_as_int(v), (l)))

// ---- shared coeff math (proven round-2..8 formulas) ----
__device__ __forceinline__ void diffks_coeffs(float f0v, float lbg, float lbp,
                                              int n, float4& lo, float4& hi) {
  float g  = 0.99f * lbg;
  float p  = lbp;
  float b0 = g * (1.0f - p);
  float a1 = g * p;
  float f0c = f0v - a1 / (b0 + a1 + 1e-7f);
  int   zc  = (int)floorf(f0c) - 2;
  float alpha = f0c - (float)zc;
  float u0 = alpha;
  float u1 = alpha - 1.0f;
  float u2 = alpha - 2.0f;
  float u3 = alpha - 3.0f;
  float u4 = alpha - 4.0f;
  float u5 = alpha - 5.0f;
  float w0 = u1 * u2 * u3 * u4 * u5 * (-1.0f / 120.0f);
  float w1 = u0 * u2 * u3 * u4 * u5 * ( 1.0f /  24.0f);
  float w2 = u0 * u1 * u3 * u4 * u5 * (-1.0f /  12.0f);
  float w3 = u0 * u1 * u2 * u4 * u5 * ( 1.0f /  12.0f);
  float w4 = u0 * u1 * u2 * u3 * u5 * (-1.0f /  24.0f);
  float w5 = u0 * u1 * u2 * u3 * u4 * ( 1.0f / 120.0f);
  lo.x = b0 * w0;                   // block0
  lo.y = fmaf(b0, w1, a1 * w0);     // block1
  lo.z = fmaf(b0, w2, a1 * w1);     // block2
  lo.w = fmaf(b0, w3, a1 * w2);     // block3
  hi.x = fmaf(b0, w4, a1 * w3);     // block4
  hi.y = fmaf(b0, w5, a1 * w4);     // block5
  hi.z = a1 * w5;                   // block6
  hi.w = __int_as_float((n - 6 - zc) & 255);   // ring base row (pos mod 256)
}

// =================== Phase 1: T matrices (run-split, 2 blocks/CU) ========
// grid 512: block = (segment bs = id>>1, run-half h = id&1). 512 threads =
// 8 waves. Round t: wave w computes samples 32t+4w+g, g=0..3. Lane l<52:
// group g=l/13 (sample), quad q=l%13 (runs 4q..4q+3 of this block's 52).
// hist[row][0..51] row-major, rows = position mod 256, rows 256..262 mirror
// 0..6 (tap windows never wrap). Row = 52 floats = 13 float4s: group reads
// 7 x ds_read_b128 at immediate offsets m*208B; q and q+8 alias banks
// (2-way, free per m136).
// Coeffs in registers: lane (t+32j) caches samples 32t+4w+j (cache A) and
// 32t+4w+2+j (cache B); per round 4x9 readlane broadcasts, 2-mask select.
__global__ __launch_bounds__(512, 4) void diffks_phase1(
    const float* __restrict__ f0, const float* __restrict__ lb,
    const float* __restrict__ x, float* __restrict__ Tg) {
  const int bs2 = blockIdx.x;
  const int bs = bs2 >> 1, h = bs2 & 1;
  const int b  = bs >> 4, s = bs & 15;
  const int n0 = s << 10;
  const int tid = threadIdx.x;
  const int w    = tid >> 6;      // wave 0..7
  const int lane = tid & 63;

  __shared__ __align__(16) float hist[HROWS * RUNS_H]; // 54.7 KB -> 2 blocks/CU

  // ---- per-lane coeff caches: 2 samples per lane ----
  float4 cLoA, cHiA, cLoB, cHiB; float cXA, cXB;
  {
    const int pA = 32 * (lane & 31) + 4 * w + (lane >> 5);
    const int pB = pA + 2;
    const size_t gA = (size_t)b * N_ + n0 + pA;
    const size_t gB = (size_t)b * N_ + n0 + pB;
    const float2 lvA = ((const float2*)lb)[gA];
    const float2 lvB = ((const float2*)lb)[gB];
    diffks_coeffs(f0[gA], lvA.x, lvA.y, pA, cLoA, cHiA);
    diffks_coeffs(f0[gB], lvB.x, lvB.y, pB, cLoB, cHiB);
    cXA = x[gA]; cXB = x[gB];
  }

  // Zero rows 152..255 (initial-state rows 153..255 + row 152 slack).
  // Rows 0..151 are written (sample p -> row p) before first read (lag>=37
  // always lands in a later 32-sample round). Mirrors 256..262 are written
  // in round 0 before any wrap-read (earliest wrap-read: sample >= 37).
  {
    float4* __restrict__ hz = (float4*)(hist + 152 * RUNS_H); // idx 1976
    for (int i = tid; i < 104 * RUNS_H / 4; i += 512)         // 1352 float4
      hz[i] = float4{0.0f, 0.0f, 0.0f, 0.0f};
  }
  __syncthreads();
  // e_r at position -1-r -> row 255-r, for this block's runs (global run
  // 52h+tid; run 103 is the particular: no delta).
  if (tid < RUNS_H && (h == 0 || tid < 51))
    hist[(255 - (RUNS_H * h + tid)) * RUNS_H + tid] = 1.0f;
  __syncthreads();

  {
    const int  g   = lane / 13;           // sample group 0..4 (>=4 idle)
    const int  q   = lane - 13 * g;       // run quad 0..12
    const bool act = (lane < 52);
    const bool s1  = (g & 1) != 0;        // select bits (hoisted masks)
    const bool s2  = (g & 2) != 0;
    const bool px  = act && (q == 12) && (h == 1);  // .w of quad 12 = run 103
    float* __restrict__ hq = hist + 4 * q;

#define SEL4(a0, a1, a2, a3) (s2 ? (s1 ? (a3) : (a2)) : (s1 ? (a1) : (a0)))

    for (int t = 0; t < 32; ++t) {
      // broadcast round-t coeffs for the wave's 4 samples (VALU readlane)
      const int lA = t, lB = t + 32;
      const float b6_0 = RL(cHiA.z, lA), b6_1 = RL(cHiA.z, lB),
                  b6_2 = RL(cHiB.z, lA), b6_3 = RL(cHiB.z, lB);
      const float b5_0 = RL(cHiA.y, lA), b5_1 = RL(cHiA.y, lB),
                  b5_2 = RL(cHiB.y, lA), b5_3 = RL(cHiB.y, lB);
      const float b4_0 = RL(cHiA.x, lA), b4_1 = RL(cHiA.x, lB),
                  b4_2 = RL(cHiB.x, lA), b4_3 = RL(cHiB.x, lB);
      const float b3_0 = RL(cLoA.w, lA), b3_1 = RL(cLoA.w, lB),
                  b3_2 = RL(cLoB.w, lA), b3_3 = RL(cLoB.w, lB);
      const float b2_0 = RL(cLoA.z, lA), b2_1 = RL(cLoA.z, lB),
                  b2_2 = RL(cLoB.z, lA), b2_3 = RL(cLoB.z, lB);
      const float b1_0 = RL(cLoA.y, lA), b1_1 = RL(cLoA.y, lB),
                  b1_2 = RL(cLoB.y, lA), b1_3 = RL(cLoB.y, lB);
      const float b0_0 = RL(cLoA.x, lA), b0_1 = RL(cLoA.x, lB),
                  b0_2 = RL(cLoB.x, lA), b0_3 = RL(cLoB.x, lB);
      const float bw_0 = RL(cHiA.w, lA), bw_1 = RL(cHiA.w, lB),
                  bw_2 = RL(cHiB.w, lA), bw_3 = RL(cHiB.w, lB);
      const float x_0  = RL(cXA,   lA), x_1  = RL(cXA,   lB),
                  x_2  = RL(cXB,   lA), x_3  = RL(cXB,   lB);

      if (act) {
        const float c0 = SEL4(b6_0, b6_1, b6_2, b6_3);  // block6 (oldest row)
        const float c1 = SEL4(b5_0, b5_1, b5_2, b5_3);
        const float c2 = SEL4(b4_0, b4_1, b4_2, b4_3);
        const float c3 = SEL4(b3_0, b3_1, b3_2, b3_3);
        const float c4 = SEL4(b2_0, b2_1, b2_2, b2_3);
        const float c5 = SEL4(b1_0, b1_1, b1_2, b1_3);
        const float c6 = SEL4(b0_0, b0_1, b0_2, b0_3);  // block0 (newest row)
        const int   base = __float_as_int(SEL4(bw_0, bw_1, bw_2, bw_3));
        const float xv   = SEL4(x_0, x_1, x_2, x_3);

        const float4* __restrict__ hr = (const float4*)(hq + base * RUNS_H);
        float4 a;
        a.x = 0.0f; a.y = 0.0f; a.z = 0.0f;
        a.w = px ? xv : 0.0f;
        {
          const float4 v0 = hr[0 * 13];   // imm offsets m*208B
          const float4 v1 = hr[1 * 13];
          const float4 v2 = hr[2 * 13];
          const float4 v3 = hr[3 * 13];
          const float4 v4 = hr[4 * 13];
          const float4 v5 = hr[5 * 13];
          const float4 v6 = hr[6 * 13];
          a.x = fmaf(c0, v0.x, a.x); a.y = fmaf(c0, v0.y, a.y);
          a.z = fmaf(c0, v0.z, a.z); a.w = fmaf(c0, v0.w, a.w);
          a.x = fmaf(c1, v1.x, a.x); a.y = fmaf(c1, v1.y, a.y);
          a.z = fmaf(c1, v1.z, a.z); a.w = fmaf(c1, v1.w, a.w);
          a.x = fmaf(c2, v2.x, a.x); a.y = fmaf(c2, v2.y, a.y);
          a.z = fmaf(c2, v2.z, a.z); a.w = fmaf(c2, v2.w, a.w);
          a.x = fmaf(c3, v3.x, a.x); a.y = fmaf(c3, v3.y, a.y);
          a.z = fmaf(c3, v3.z, a.z); a.w = fmaf(c3, v3.w, a.w);
          a.x = fmaf(c4, v4.x, a.x); a.y = fmaf(c4, v4.y, a.y);
          a.z = fmaf(c4, v4.z, a.z); a.w = fmaf(c4, v4.w, a.w);
          a.x = fmaf(c5, v5.x, a.x); a.y = fmaf(c5, v5.y, a.y);
          a.z = fmaf(c5, v5.z, a.z); a.w = fmaf(c5, v5.w, a.w);
          a.x = fmaf(c6, v6.x, a.x); a.y = fmaf(c6, v6.y, a.y);
          a.z = fmaf(c6, v6.z, a.z); a.w = fmaf(c6, v6.w, a.w);
        }
        const int p   = 32 * t + 4 * w + g;
        const int wsl = p & 255;
        *(float4*)(hq + wsl * RUNS_H) = a;
        // mirror rows 0..6 -> 256..262 (samples p === 0..6 mod 256)
        if (((t & 7) == 0) && (w < 2) && (wsl < 7))
          *(float4*)(hq + (wsl + 256) * RUNS_H) = a;
      }
      __syncthreads();   // publish this round's 32 samples to all waves
    }
#undef SEL4
  }

  // emit RUNS-MAJOR slab: T[52h+rl][j] = run rl at position 1023-j
  float* __restrict__ T = Tg + ((size_t)bs * RUNS + RUNS_H * h) * RUNS;
  for (int idx = tid; idx < RUNS_H * RUNS; idx += 512) {
    const int rl = idx / RUNS;
    const int j  = idx - rl * RUNS;
    T[idx] = (j < 103) ? hist[(255 - j) * RUNS_H + rl] : 0.0f;
  }
}

// =================== Phase 2: serial state composition ===================
// grid 16 (batch), block 832 = 104 j-threads x 8 k-slices.
// state_{s+1}[j] = sum_{r=0..103} T[r][j] * cur[r], with cur[103] == 1
// (run 103 is the particular tail). Lanes = consecutive j -> coalesced loads.
// Double-buffered prefetch with GUARANTEED static register indexing.
#define P2_STEP(s_, tv_)                                                      \
  {                                                                           \
    if (q == 0) states[((size_t)b * S_ + (s_)) * RUNS + j] = cur[j];          \
    float acc = 0.0f;                                                         \
    _Pragma("unroll")                                                         \
    for (int k = 0; k < 13; ++k) acc = fmaf(tv_[k], cur[r0 + k], acc);        \
    if ((s_) + 2 < S_) {                                                      \
      const float* __restrict__ Tn = Tb + (size_t)((s_) + 2) * RUNS * RUNS;   \
      _Pragma("unroll")                                                       \
      for (int k = 0; k < 13; ++k) tv_[k] = Tn[(size_t)(r0 + k) * RUNS + j];  \
    }                                                                         \
    part[q][j] = acc;                                                         \
    __syncthreads();                                                          \
    if (q == 0) {                                                             \
      float v = 0.0f;                                                         \
      _Pragma("unroll")                                                       \
      for (int qq = 0; qq < 8; ++qq) v += part[qq][j];                        \
      cur[j] = (j < 103) ? v : 1.0f;                                          \
    }                                                                         \
    __syncthreads();                                                          \
  }

__global__ __launch_bounds__(832) void diffks_phase2(
    const float* __restrict__ Tg, float* __restrict__ states) {
  const int b   = blockIdx.x;
  const int tid = threadIdx.x;
  const int j   = tid % RUNS;      // 0..103
  const int q   = tid / RUNS;      // 0..7
  const int r0  = 13 * q;
  __shared__ float cur[RUNS];
  __shared__ float part[8][105];   // 105 stride: conflict-free reduce
  if (tid < 103) cur[tid] = 0.0f;
  if (tid == 103) cur[103] = 1.0f; // particular weight, never overwritten
  __syncthreads();

  const float* __restrict__ Tb = Tg + (size_t)b * S_ * RUNS * RUNS;
  float tvA[13], tvB[13];
#pragma unroll
  for (int k = 0; k < 13; ++k)
    tvA[k] = Tb[(size_t)(r0 + k) * RUNS + j];                       // seg 0
#pragma unroll
  for (int k = 0; k < 13; ++k)
    tvB[k] = Tb[(size_t)RUNS * RUNS + (size_t)(r0 + k) * RUNS + j]; // seg 1

#pragma unroll
  for (int sp = 0; sp < 8; ++sp) {
    P2_STEP(2 * sp,     tvA)
    P2_STEP(2 * sp + 1, tvB)
  }
}

// =================== Phase 3: exact per-segment re-run ===================
// grid 256, block 256 (4 waves): all stage coeffs (recomputed from f0/lb/x:
// 16B/sample), wave 0 runs the 28-iter scan, all flush.
__global__ __launch_bounds__(256) void diffks_phase3(
    const float* __restrict__ f0, const float* __restrict__ lb,
    const float* __restrict__ x, const float* __restrict__ states,
    float* __restrict__ y) {
  const int bs = blockIdx.x;
  const int b  = bs >> 4, s = bs & 15;
  const int n0 = s << 10;
  const int tid = threadIdx.x;

  __shared__ __align__(16) float ring[512];   // mirrored mod-256 ring
  __shared__ float4 sC[2 * NSEG];             // interleaved lo/hi
  __shared__ float  sX[NSEG];
  __shared__ float  sY[NSEG];

#pragma unroll
  for (int k = 0; k < 2; ++k) ring[tid + 256 * k] = 0.0f;
  {
    const size_t gb = (size_t)b * N_ + n0;
    const float*  __restrict__ f0b = f0 + gb;
    const float2* __restrict__ lbb = (const float2*)(lb + 2 * gb);
    const float*  __restrict__ xb  = x + gb;
    // batch all 4 rounds of loads, then compute
    float  vf[4]; float2 vl[4]; float vx[4];
#pragma unroll
    for (int k = 0; k < 4; ++k) {
      const int i = tid + 256 * k;
      vf[k] = f0b[i]; vl[k] = lbb[i]; vx[k] = xb[i];
    }
#pragma unroll
    for (int k = 0; k < 4; ++k) {
      const int i = tid + 256 * k;
      float4 lo, hi;
      diffks_coeffs(vf[k], vl[k].x, vl[k].y, n0 + i, lo, hi);
      sC[2 * i] = lo; sC[2 * i + 1] = hi; sX[i] = vx[k];
    }
  }
  __syncthreads();
  // incoming state k at position n0-1-k -> row 255-k (+ mirror). Hot-loop
  // writes only reach row 255-k at p=255-k > 102-k = last read of state k.
  const float* __restrict__ st = states + (size_t)bs * RUNS;
  if (tid < 103) {
    const float v = st[tid];
    ring[255 - tid] = v;
    ring[511 - tid] = v;
  }
  __syncthreads();

  if (tid < 64) {
    const int lane = tid;
    const bool act = (lane < CHUNK);
    for (int t = 0; t < NITER; ++t) {
      const int p = t * CHUNK + lane;
      if (act && p < NSEG) {
        const float4 lo = sC[2 * p];
        const float4 hi = sC[2 * p + 1];
        const float  xv = sX[p];
        const int base = __float_as_int(hi.w);   // (p-6-zc)&255
        const float r0 = ring[base + 0];
        const float r1 = ring[base + 1];
        const float r2 = ring[base + 2];
        const float r3 = ring[base + 3];
        const float r4 = ring[base + 4];
        const float r5 = ring[base + 5];
        const float r6 = ring[base + 6];
        const float s0 = fmaf(lo.x, r6, xv);
        const float s1 = fmaf(lo.y, r5, lo.z * r4);
        const float s2 = fmaf(lo.w, r3, hi.x * r2);
        const float s3 = fmaf(hi.y, r1, hi.z * r0);
        const float yv = (s0 + s1) + (s2 + s3);
        const int wsl = p & 255;
        ring[wsl]       = yv;
        ring[wsl + 256] = yv;
        sY[p] = yv;
      }
      __builtin_amdgcn_wave_barrier();
      asm volatile("" ::: "memory");
    }
  }
  __syncthreads();

  float4* __restrict__ yb = (float4*)(y + (size_t)b * N_ + n0);
  yb[tid] = ((const float4*)sY)[tid];
}

// =================== Fallback (proven round-2 path) ===================
__global__ __launch_bounds__(256) void diffks_coeff_fb(
    const float* __restrict__ f0, const float* __restrict__ lb,
    float* __restrict__ cw, int total, int Nmask) {
  int idx = blockIdx.x * blockDim.x + threadIdx.x;
  if (idx >= total) return;
  float4 lo, hi;
  diffks_coeffs(f0[idx], lb[2 * idx], lb[2 * idx + 1], idx & Nmask, lo, hi);
  float4* out4 = (float4*)cw;
  out4[2 * idx]     = lo;
  out4[2 * idx + 1] = hi;
}

__global__ __launch_bounds__(64) void diffks_scan_fb(
    const float* __restrict__ x, const float* __restrict__ cw,
    float* __restrict__ y, int N) {
  const int b    = blockIdx.x;
  const int lane = threadIdx.x;
  __shared__ float ring[512];
#pragma unroll
  for (int i = 0; i < 8; ++i) ring[lane + 64 * i] = 0.0f;
  __builtin_amdgcn_wave_barrier();
  asm volatile("" ::: "memory");
  const float4* __restrict__ c4 = (const float4*)(cw + (size_t)b * N * 8);
  const float*  __restrict__ xb = x + (size_t)b * N;
  float*        __restrict__ yb = y + (size_t)b * N;
  const bool act = (lane < CHUNK);
  const int nIter = (N + CHUNK - 1) / CHUNK;
  for (int t = 0; t < nIter; ++t) {
    const int n = t * CHUNK + lane;
    if (act && n < N) {
      const float4 lo = c4[2 * n];
      const float4 hi = c4[2 * n + 1];
      const float  xv = xb[n];
      const int base = __float_as_int(hi.w);
      const float r0 = ring[base + 0];
      const float r1 = ring[base + 1];
      const float r2 = ring[base + 2];
      const float r3 = ring[base + 3];
      const float r4 = ring[base + 4];
      const float r5 = ring[base + 5];
      const float r6 = ring[base + 6];
      const float s0 = fmaf(lo.x, r6, xv);
      const float s1 = fmaf(lo.y, r5, lo.z * r4);
      const float s2 = fmaf(lo.w, r3, hi.x * r2);
      const float s3 = fmaf(hi.y, r1, hi.z * r0);
      const float yv = (s0 + s1) + (s2 + s3);
      ring[n & 255]         = yv;
      ring[(n & 255) + 256] = yv;
      yb[n] = yv;
    }
    __builtin_amdgcn_wave_barrier();
    asm volatile("" ::: "memory");
  }
}

extern "C" void kernel_launch(void* const* d_in, const int* in_sizes, int n_in,
                              void* d_out, int out_size, void* d_ws, size_t ws_size,
                              hipStream_t stream) {
  const float* f0 = (const float*)d_in[0];
  const float* x  = (const float*)d_in[1];
  const float* lb = (const float*)d_in[2];
  float* out = (float*)d_out;

  const int total = in_sizes[0];
  const size_t need = (size_t)(TG_FLOATS + ST_FLOATS) * 4;

  if (total == B_ * N_ && ws_size >= need) {
    float* Tg = (float*)d_ws;
    float* st = Tg + TG_FLOATS;
    diffks_phase1<<<2 * B_ * S_, 512, 0, stream>>>(f0, lb, x, Tg);
    diffks_phase2<<<B_, 832, 0, stream>>>(Tg, st);
    diffks_phase3<<<B_ * S_, 256, 0, stream>>>(f0, lb, x, st, out);
  } else {
    const int N = total / B_;
    float* cw = (float*)d_ws;
    diffks_coeff_fb<<<(total + 255) / 256, 256, 0, stream>>>(f0, lb, cw, total, N - 1);
    diffks_scan_fb<<<B_, 64, 0, stream>>>(x, cw, out, N);
  }
}

// Round 8
// 105.518 us; speedup vs baseline: 1.2226x; 1.2226x over previous
//
#include <hip/hip_runtime.h>
#include <math.h>

// DiffKS: time-varying 7-tap sparse IIR.
//   y[n] = x[n] + sum_{i=0..6} block_i[n] * y[n - zc[n] - i],  zc in [37,97].
// Max lag 103 -> 103-sample state. Linear => segmented superposition:
//   phase1: ROUND-18 = r7 run-split MINUS the readlane storm. 512 blocks x
//           512 threads; block (bs,h) evolves 52 runs; hist 263x52 = 54.7KB;
//           coeffs in LDS (512-sample halves, restaged at t=16, 18KB) read
//           PER-LANE (4 distinct addrs/wave ~ broadcast). 72.7KB/block ->
//           2 blocks/CU overlap each other's barrier stalls.
//           Cost model (fits r0/r6/r7): DS = bytes/128B + 4cy/inst;
//           r7 failed on 36 v_readlane + selects ~= 2000 VALU cy/round
//           (VALUBusy 61%); this cuts VALU to ~80 insts/wave-round.
//   phase2: serial state composition, coalesced split-K (round-8 spill-proof
//           macro: tvA/tvB always statically indexed).
//   phase3: exact per-segment re-run with known incoming state (256 blocks).
// DEAD ENDS (do not revisit): cross-block sync in-kernel (spin flags 124us,
// coop grid-sync 264us); Cg coeff detour (+16.8MB HBM); chunked hist layout
// (write conflicts); readlane coeff broadcast (VALU-serial, 61% VALUBusy);
// 1-block/CU inner-loop rewrites (lock-step barrier floor ~27us).

#define B_    16
#define N_    16384
#define S_    16
#define NSEG  1024
#define NITER 28      // ceil(1024/37) for phase3
#define RUNS  104     // 103 unit columns + 1 particular
#define RUNS_H 52     // runs per phase1 block (run-split)
#define CHUNK 37      // min dependency distance (zc >= 37)
#define HROWS 263     // 256 ring rows + 7 mirror rows (rows 256..262 = 0..6)

#define TG_FLOATS (B_ * S_ * RUNS * RUNS)
#define ST_FLOATS (B_ * S_ * RUNS)

// ---- shared coeff math (proven round-2..8 formulas) ----
__device__ __forceinline__ void diffks_coeffs(float f0v, float lbg, float lbp,
                                              int n, float4& lo, float4& hi) {
  float g  = 0.99f * lbg;
  float p  = lbp;
  float b0 = g * (1.0f - p);
  float a1 = g * p;
  float f0c = f0v - a1 / (b0 + a1 + 1e-7f);
  int   zc  = (int)floorf(f0c) - 2;
  float alpha = f0c - (float)zc;
  float u0 = alpha;
  float u1 = alpha - 1.0f;
  float u2 = alpha - 2.0f;
  float u3 = alpha - 3.0f;
  float u4 = alpha - 4.0f;
  float u5 = alpha - 5.0f;
  float w0 = u1 * u2 * u3 * u4 * u5 * (-1.0f / 120.0f);
  float w1 = u0 * u2 * u3 * u4 * u5 * ( 1.0f /  24.0f);
  float w2 = u0 * u1 * u3 * u4 * u5 * (-1.0f /  12.0f);
  float w3 = u0 * u1 * u2 * u4 * u5 * ( 1.0f /  12.0f);
  float w4 = u0 * u1 * u2 * u3 * u5 * (-1.0f /  24.0f);
  float w5 = u0 * u1 * u2 * u3 * u4 * ( 1.0f / 120.0f);
  lo.x = b0 * w0;                   // block0
  lo.y = fmaf(b0, w1, a1 * w0);     // block1
  lo.z = fmaf(b0, w2, a1 * w1);     // block2
  lo.w = fmaf(b0, w3, a1 * w2);     // block3
  hi.x = fmaf(b0, w4, a1 * w3);     // block4
  hi.y = fmaf(b0, w5, a1 * w4);     // block5
  hi.z = a1 * w5;                   // block6
  hi.w = __int_as_float((n - 6 - zc) & 255);   // ring base row (pos mod 256)
}

// =================== Phase 1: T matrices (run-split, LDS coeffs) =========
// grid 512: block = (segment bs = id>>1, run-half h = id&1). 512 threads =
// 8 waves. Round t: wave w computes samples 32t+4w+g, g=0..3. Lane l<52:
// group g=l/13 (sample), quad q=l%13 (runs 4q..4q+3 of this block's 52).
// hist[row][0..51] row-major (stride 52 floats); rows = position mod 256;
// rows 256..262 mirror 0..6 (tap windows never wrap). Tap m for all 4
// groups = ONE 52-lane ds_read_b128 at per-lane row base_g + imm m*13.
// Coeffs: sC[2i]=lo, sC[2i+1]=hi, sXc[i]=x for the current 512-sample half,
// read per-lane (4 distinct addresses/wave -> near-broadcast sweeps).
__global__ __launch_bounds__(512, 4) void diffks_phase1(
    const float* __restrict__ f0, const float* __restrict__ lb,
    const float* __restrict__ x, float* __restrict__ Tg) {
  const int bs2 = blockIdx.x;
  const int bs = bs2 >> 1, h = bs2 & 1;
  const int b  = bs >> 4, s = bs & 15;
  const int n0 = s << 10;
  const int tid = threadIdx.x;
  const int w    = tid >> 6;      // wave 0..7
  const int lane = tid & 63;

  __shared__ __align__(16) float  hist[HROWS * RUNS_H]; // 54.7 KB
  __shared__ __align__(16) float4 sC[2 * 512];          // 16 KB (half-staged)
  __shared__ float sXc[512];                            // 2 KB
  // total 72.7 KB -> 2 blocks/CU

  // ---- stage coeff half 0 (samples 0..511), one sample per thread ----
  {
    const size_t gi = (size_t)b * N_ + n0 + tid;
    const float2 lv = ((const float2*)lb)[gi];
    float4 lo, hi;
    diffks_coeffs(f0[gi], lv.x, lv.y, tid, lo, hi);
    sC[2 * tid] = lo; sC[2 * tid + 1] = hi; sXc[tid] = x[gi];
  }

  // Zero rows 152..255 (initial-state rows 153..255 + row 152 slack).
  // Rows 0..151 are written (sample p -> row p) before first read (lag>=37).
  // Mirrors 256..262 are written in round 0 before any wrap-read.
  {
    float4* __restrict__ hz = (float4*)(hist + 152 * RUNS_H);
    for (int i = tid; i < 104 * RUNS_H / 4; i += 512)
      hz[i] = float4{0.0f, 0.0f, 0.0f, 0.0f};
  }
  __syncthreads();
  // e_r at position -1-r -> row 255-r, this block's runs (global 52h+tid;
  // run 103 is the particular: no delta).
  if (tid < RUNS_H && (h == 0 || tid < 51))
    hist[(255 - (RUNS_H * h + tid)) * RUNS_H + tid] = 1.0f;
  __syncthreads();

  {
    const int  g   = lane / 13;           // sample group 0..4 (>=4 idle)
    const int  q   = lane - 13 * g;       // run quad 0..12
    const bool act = (lane < 52);
    const bool px  = act && (q == 12) && (h == 1);  // .w of quad 12 = run 103
    float* __restrict__ hq = hist + 4 * q;

    for (int t = 0; t < 32; ++t) {
      if (t == 16) {
        // restage half 1 (samples 512..1023). Round-15's trailing barrier
        // guarantees no pending reads of half 0.
        const int p = 512 + tid;
        const size_t gi = (size_t)b * N_ + n0 + p;
        const float2 lv = ((const float2*)lb)[gi];
        float4 lo, hi;
        diffks_coeffs(f0[gi], lv.x, lv.y, p, lo, hi);
        sC[2 * tid] = lo; sC[2 * tid + 1] = hi; sXc[tid] = x[gi];
        __syncthreads();
      }

      if (act) {
        const int p  = 32 * t + 4 * w + g;     // this lane's sample
        const int ps = p & 511;                // index into current half
        const float4 lo = sC[2 * ps];          // 4 distinct addrs per wave
        const float4 hi = sC[2 * ps + 1];
        const float  xv = sXc[ps];

        const int base = __float_as_int(hi.w); // row of oldest tap, 0..255
        const float4* __restrict__ hr = (const float4*)(hq + base * RUNS_H);
        float4 a;
        a.x = 0.0f; a.y = 0.0f; a.z = 0.0f;
        a.w = px ? xv : 0.0f;
        const float c0 = hi.z, c1 = hi.y, c2 = hi.x, c3 = lo.w,
                    c4 = lo.z, c5 = lo.y, c6 = lo.x;
        {
          const float4 v0 = hr[0 * 13];        // imm offsets m*208B
          const float4 v1 = hr[1 * 13];
          const float4 v2 = hr[2 * 13];
          const float4 v3 = hr[3 * 13];
          const float4 v4 = hr[4 * 13];
          const float4 v5 = hr[5 * 13];
          const float4 v6 = hr[6 * 13];
          a.x = fmaf(c0, v0.x, a.x); a.y = fmaf(c0, v0.y, a.y);
          a.z = fmaf(c0, v0.z, a.z); a.w = fmaf(c0, v0.w, a.w);
          a.x = fmaf(c1, v1.x, a.x); a.y = fmaf(c1, v1.y, a.y);
          a.z = fmaf(c1, v1.z, a.z); a.w = fmaf(c1, v1.w, a.w);
          a.x = fmaf(c2, v2.x, a.x); a.y = fmaf(c2, v2.y, a.y);
          a.z = fmaf(c2, v2.z, a.z); a.w = fmaf(c2, v2.w, a.w);
          a.x = fmaf(c3, v3.x, a.x); a.y = fmaf(c3, v3.y, a.y);
          a.z = fmaf(c3, v3.z, a.z); a.w = fmaf(c3, v3.w, a.w);
          a.x = fmaf(c4, v4.x, a.x); a.y = fmaf(c4, v4.y, a.y);
          a.z = fmaf(c4, v4.z, a.z); a.w = fmaf(c4, v4.w, a.w);
          a.x = fmaf(c5, v5.x, a.x); a.y = fmaf(c5, v5.y, a.y);
          a.z = fmaf(c5, v5.z, a.z); a.w = fmaf(c5, v5.w, a.w);
          a.x = fmaf(c6, v6.x, a.x); a.y = fmaf(c6, v6.y, a.y);
          a.z = fmaf(c6, v6.z, a.z); a.w = fmaf(c6, v6.w, a.w);
        }
        const int wsl = p & 255;
        *(float4*)(hq + wsl * RUNS_H) = a;
        // mirror rows 0..6 -> 256..262 (samples p === 0..6 mod 256)
        if (((t & 7) == 0) && (w < 2) && (wsl < 7))
          *(float4*)(hq + (wsl + 256) * RUNS_H) = a;
      }
      __syncthreads();   // publish this round's 32 samples to all waves
    }
  }

  // emit RUNS-MAJOR slab: T[52h+rl][j] = run rl at position 1023-j
  float* __restrict__ T = Tg + ((size_t)bs * RUNS + RUNS_H * h) * RUNS;
  for (int idx = tid; idx < RUNS_H * RUNS; idx += 512) {
    const int rl = idx / RUNS;
    const int j  = idx - rl * RUNS;
    T[idx] = (j < 103) ? hist[(255 - j) * RUNS_H + rl] : 0.0f;
  }
}

// =================== Phase 2: serial state composition ===================
// grid 16 (batch), block 832 = 104 j-threads x 8 k-slices.
// state_{s+1}[j] = sum_{r=0..103} T[r][j] * cur[r], with cur[103] == 1
// (run 103 is the particular tail). Lanes = consecutive j -> coalesced loads.
// Double-buffered prefetch with GUARANTEED static register indexing.
#define P2_STEP(s_, tv_)                                                      \
  {                                                                           \
    if (q == 0) states[((size_t)b * S_ + (s_)) * RUNS + j] = cur[j];          \
    float acc = 0.0f;                                                         \
    _Pragma("unroll")                                                         \
    for (int k = 0; k < 13; ++k) acc = fmaf(tv_[k], cur[r0 + k], acc);        \
    if ((s_) + 2 < S_) {                                                      \
      const float* __restrict__ Tn = Tb + (size_t)((s_) + 2) * RUNS * RUNS;   \
      _Pragma("unroll")                                                       \
      for (int k = 0; k < 13; ++k) tv_[k] = Tn[(size_t)(r0 + k) * RUNS + j];  \
    }                                                                         \
    part[q][j] = acc;                                                         \
    __syncthreads();                                                          \
    if (q == 0) {                                                             \
      float v = 0.0f;                                                         \
      _Pragma("unroll")                                                       \
      for (int qq = 0; qq < 8; ++qq) v += part[qq][j];                        \
      cur[j] = (j < 103) ? v : 1.0f;                                          \
    }                                                                         \
    __syncthreads();                                                          \
  }

__global__ __launch_bounds__(832) void diffks_phase2(
    const float* __restrict__ Tg, float* __restrict__ states) {
  const int b   = blockIdx.x;
  const int tid = threadIdx.x;
  const int j   = tid % RUNS;      // 0..103
  const int q   = tid / RUNS;      // 0..7
  const int r0  = 13 * q;
  __shared__ float cur[RUNS];
  __shared__ float part[8][105];   // 105 stride: conflict-free reduce
  if (tid < 103) cur[tid] = 0.0f;
  if (tid == 103) cur[103] = 1.0f; // particular weight, never overwritten
  __syncthreads();

  const float* __restrict__ Tb = Tg + (size_t)b * S_ * RUNS * RUNS;
  float tvA[13], tvB[13];
#pragma unroll
  for (int k = 0; k < 13; ++k)
    tvA[k] = Tb[(size_t)(r0 + k) * RUNS + j];                       // seg 0
#pragma unroll
  for (int k = 0; k < 13; ++k)
    tvB[k] = Tb[(size_t)RUNS * RUNS + (size_t)(r0 + k) * RUNS + j]; // seg 1

#pragma unroll
  for (int sp = 0; sp < 8; ++sp) {
    P2_STEP(2 * sp,     tvA)
    P2_STEP(2 * sp + 1, tvB)
  }
}

// =================== Phase 3: exact per-segment re-run ===================
// grid 256, block 256 (4 waves): all stage coeffs (recomputed from f0/lb/x:
// 16B/sample), wave 0 runs the 28-iter scan, all flush.
__global__ __launch_bounds__(256) void diffks_phase3(
    const float* __restrict__ f0, const float* __restrict__ lb,
    const float* __restrict__ x, const float* __restrict__ states,
    float* __restrict__ y) {
  const int bs = blockIdx.x;
  const int b  = bs >> 4, s = bs & 15;
  const int n0 = s << 10;
  const int tid = threadIdx.x;

  __shared__ __align__(16) float ring[512];   // mirrored mod-256 ring
  __shared__ float4 sC[2 * NSEG];             // interleaved lo/hi
  __shared__ float  sX[NSEG];
  __shared__ float  sY[NSEG];

#pragma unroll
  for (int k = 0; k < 2; ++k) ring[tid + 256 * k] = 0.0f;
  {
    const size_t gb = (size_t)b * N_ + n0;
    const float*  __restrict__ f0b = f0 + gb;
    const float2* __restrict__ lbb = (const float2*)(lb + 2 * gb);
    const float*  __restrict__ xb  = x + gb;
    // batch all 4 rounds of loads, then compute
    float  vf[4]; float2 vl[4]; float vx[4];
#pragma unroll
    for (int k = 0; k < 4; ++k) {
      const int i = tid + 256 * k;
      vf[k] = f0b[i]; vl[k] = lbb[i]; vx[k] = xb[i];
    }
#pragma unroll
    for (int k = 0; k < 4; ++k) {
      const int i = tid + 256 * k;
      float4 lo, hi;
      diffks_coeffs(vf[k], vl[k].x, vl[k].y, n0 + i, lo, hi);
      sC[2 * i] = lo; sC[2 * i + 1] = hi; sX[i] = vx[k];
    }
  }
  __syncthreads();
  // incoming state k at position n0-1-k -> row 255-k (+ mirror). Hot-loop
  // writes only reach row 255-k at p=255-k > 102-k = last read of state k.
  const float* __restrict__ st = states + (size_t)bs * RUNS;
  if (tid < 103) {
    const float v = st[tid];
    ring[255 - tid] = v;
    ring[511 - tid] = v;
  }
  __syncthreads();

  if (tid < 64) {
    const int lane = tid;
    const bool act = (lane < CHUNK);
    for (int t = 0; t < NITER; ++t) {
      const int p = t * CHUNK + lane;
      if (act && p < NSEG) {
        const float4 lo = sC[2 * p];
        const float4 hi = sC[2 * p + 1];
        const float  xv = sX[p];
        const int base = __float_as_int(hi.w);   // (p-6-zc)&255
        const float r0 = ring[base + 0];
        const float r1 = ring[base + 1];
        const float r2 = ring[base + 2];
        const float r3 = ring[base + 3];
        const float r4 = ring[base + 4];
        const float r5 = ring[base + 5];
        const float r6 = ring[base + 6];
        const float s0 = fmaf(lo.x, r6, xv);
        const float s1 = fmaf(lo.y, r5, lo.z * r4);
        const float s2 = fmaf(lo.w, r3, hi.x * r2);
        const float s3 = fmaf(hi.y, r1, hi.z * r0);
        const float yv = (s0 + s1) + (s2 + s3);
        const int wsl = p & 255;
        ring[wsl]       = yv;
        ring[wsl + 256] = yv;
        sY[p] = yv;
      }
      __builtin_amdgcn_wave_barrier();
      asm volatile("" ::: "memory");
    }
  }
  __syncthreads();

  float4* __restrict__ yb = (float4*)(y + (size_t)b * N_ + n0);
  yb[tid] = ((const float4*)sY)[tid];
}

// =================== Fallback (proven round-2 path) ===================
__global__ __launch_bounds__(256) void diffks_coeff_fb(
    const float* __restrict__ f0, const float* __restrict__ lb,
    float* __restrict__ cw, int total, int Nmask) {
  int idx = blockIdx.x * blockDim.x + threadIdx.x;
  if (idx >= total) return;
  float4 lo, hi;
  diffks_coeffs(f0[idx], lb[2 * idx], lb[2 * idx + 1], idx & Nmask, lo, hi);
  float4* out4 = (float4*)cw;
  out4[2 * idx]     = lo;
  out4[2 * idx + 1] = hi;
}

__global__ __launch_bounds__(64) void diffks_scan_fb(
    const float* __restrict__ x, const float* __restrict__ cw,
    float* __restrict__ y, int N) {
  const int b    = blockIdx.x;
  const int lane = threadIdx.x;
  __shared__ float ring[512];
#pragma unroll
  for (int i = 0; i < 8; ++i) ring[lane + 64 * i] = 0.0f;
  __builtin_amdgcn_wave_barrier();
  asm volatile("" ::: "memory");
  const float4* __restrict__ c4 = (const float4*)(cw + (size_t)b * N * 8);
  const float*  __restrict__ xb = x + (size_t)b * N;
  float*        __restrict__ yb = y + (size_t)b * N;
  const bool act = (lane < CHUNK);
  const int nIter = (N + CHUNK - 1) / CHUNK;
  for (int t = 0; t < nIter; ++t) {
    const int n = t * CHUNK + lane;
    if (act && n < N) {
      const float4 lo = c4[2 * n];
      const float4 hi = c4[2 * n + 1];
      const float  xv = xb[n];
      const int base = __float_as_int(hi.w);
      const float r0 = ring[base + 0];
      const float r1 = ring[base + 1];
      const float r2 = ring[base + 2];
      const float r3 = ring[base + 3];
      const float r4 = ring[base + 4];
      const float r5 = ring[base + 5];
      const float r6 = ring[base + 6];
      const float s0 = fmaf(lo.x, r6, xv);
      const float s1 = fmaf(lo.y, r5, lo.z * r4);
      const float s2 = fmaf(lo.w, r3, hi.x * r2);
      const float s3 = fmaf(hi.y, r1, hi.z * r0);
      const float yv = (s0 + s1) + (s2 + s3);
      ring[n & 255]         = yv;
      ring[(n & 255) + 256] = yv;
      yb[n] = yv;
    }
    __builtin_amdgcn_wave_barrier();
    asm volatile("" ::: "memory");
  }
}

extern "C" void kernel_launch(void* const* d_in, const int* in_sizes, int n_in,
                              void* d_out, int out_size, void* d_ws, size_t ws_size,
                              hipStream_t stream) {
  const float* f0 = (const float*)d_in[0];
  const float* x  = (const float*)d_in[1];
  const float* lb = (const float*)d_in[2];
  float* out = (float*)d_out;

  const int total = in_sizes[0];
  const size_t need = (size_t)(TG_FLOATS + ST_FLOATS) * 4;

  if (total == B_ * N_ && ws_size >= need) {
    float* Tg = (float*)d_ws;
    float* st = Tg + TG_FLOATS;
    diffks_phase1<<<2 * B_ * S_, 512, 0, stream>>>(f0, lb, x, Tg);
    diffks_phase2<<<B_, 832, 0, stream>>>(Tg, st);
    diffks_phase3<<<B_ * S_, 256, 0, stream>>>(f0, lb, x, st, out);
  } else {
    const int N = total / B_;
    float* cw = (float*)d_ws;
    diffks_coeff_fb<<<(total + 255) / 256, 256, 0, stream>>>(f0, lb, cw, total, N - 1);
    diffks_scan_fb<<<B_, 64, 0, stream>>>(x, cw, out, N);
  }
}